// Round 10
// baseline (210.613 us; speedup 1.0000x reference)
//
#include <hip/hip_runtime.h>
#include <hip/hip_bf16.h>

#define EE 768
#define HH 12
#define DD 64
#define BB 2
#define SS 2048
#define MM (BB*SS)          // 4096
#define NT (MM*EE)          // 3,145,728 elements (also B*H*S*D)
#define NW (EE*EE)          // 589,824

typedef short short8 __attribute__((ext_vector_type(8)));   // 8 bf16 = 4 VGPR (MFMA A/B frag)
typedef float f32x4 __attribute__((ext_vector_type(4)));    // MFMA C/D frag

static __device__ __forceinline__ unsigned short f2bf(float f) {
    unsigned int u = __float_as_uint(f);
    u += 0x7fffu + ((u >> 16) & 1u);      // round-to-nearest-even
    return (unsigned short)(u >> 16);
}

// async 16B global->LDS. LDS dest = wave-uniform base + lane*16 (HW rule).
static __device__ __forceinline__ void gl16(const void* g, void* l) {
    __builtin_amdgcn_global_load_lds(
        (const __attribute__((address_space(1))) unsigned int*)g,
        (__attribute__((address_space(3))) unsigned int*)l, 16, 0, 0);
}

// Swizzled byte offset in a [R][64] bf16 LDS tile (128B rows, 8x16B chunks).
// Staging pre-swizzles the per-lane GLOBAL source chunk ((l&7)^(l>>3)) so the
// linear gl16 dest holds swizzled content; reads via swz() are conflict-free
// (rule #21: both-sides-or-neither).
static __device__ __forceinline__ int swz(int row, int chunk) {
    return row * 128 + ((chunk ^ (row & 7)) << 4);
}

// ---------------------------------------------------------------------------
// fp32 -> bf16 pre-convert, all 7 tensors in one launch (memory-bound).
// ---------------------------------------------------------------------------
__global__ __launch_bounds__(256) void cvt_all_kernel(
    const float* __restrict__ xq, const float* __restrict__ xk, const float* __restrict__ xv,
    const float* __restrict__ wq, const float* __restrict__ wk,
    const float* __restrict__ wv, const float* __restrict__ wo,
    unsigned short* __restrict__ oq, unsigned short* __restrict__ ok, unsigned short* __restrict__ ov,
    unsigned short* __restrict__ owq, unsigned short* __restrict__ owk,
    unsigned short* __restrict__ owv, unsigned short* __restrict__ owo)
{
    const int XQ = NT / 4;   // quads per x tensor
    const int WQ = NW / 4;   // quads per W tensor
    const int idx = blockIdx.x * 256 + threadIdx.x;
    const float* s;
    unsigned short* d;
    int off;
    if (idx < 3 * XQ) {
        const int r = idx / XQ;
        off = idx - r * XQ;
        s = (r == 0) ? xq : (r == 1) ? xk : xv;
        d = (r == 0) ? oq : (r == 1) ? ok : ov;
    } else {
        const int j = idx - 3 * XQ;
        const int r = j / WQ;
        off = j - r * WQ;
        s = (r == 0) ? wq : (r == 1) ? wk : (r == 2) ? wv : wo;
        d = (r == 0) ? owq : (r == 1) ? owk : (r == 2) ? owv : owo;
    }
    float4 f = ((const float4*)s)[off];
    ushort4 u;
    u.x = f2bf(f.x); u.y = f2bf(f.y); u.z = f2bf(f.z); u.w = f2bf(f.w);
    ((ushort4*)d)[off] = u;
}

// ---------------------------------------------------------------------------
// Kernel 1: QKV projection, MFMA, BN=128 (TWO heads per block).
// grid (MM/128, 18): by/6 = proj (0=q 1=k 2=v), by%6 = head-pair hp.
// BM=128 BN=128 BK=64, 256 thr = 4 waves (2Mx2N), per-wave 64x64
// (Mrep=4, Nrep=4, 32 MFMA/K-step; 64 FLOP per staged byte).
// Wave wn's 64 cols == one full head -> l2-norm is wave-local (no LDS reduce).
// q folds SCALE*log2e so attention uses exp2. v -> transposed [bh][d][s]
// via a [128 s][128 d] reuse of the 32 KB As|Bs LDS.
// ---------------------------------------------------------------------------
__global__ __launch_bounds__(256) void qkv_mfma_kernel(
    const unsigned short* __restrict__ xq, const unsigned short* __restrict__ xk,
    const unsigned short* __restrict__ xv,
    const unsigned short* __restrict__ Wq, const float* __restrict__ bq,
    const unsigned short* __restrict__ Wk, const float* __restrict__ bk,
    const unsigned short* __restrict__ Wv, const float* __restrict__ bv,
    unsigned short* __restrict__ qo, unsigned short* __restrict__ ko,
    unsigned short* __restrict__ vo)
{
    __shared__ short SMEM[128 * 128];          // 32 KB: As | Bs, reused for V-transpose
    short* As = SMEM;                          // [128 m][64 k] swizzled
    short* Bs = SMEM + 128 * 64;               // [128 n][64 k] swizzled

    const int tid = threadIdx.x;
    const int bm  = blockIdx.x * 128;
    const int by  = blockIdx.y;
    const int proj = by / 6;
    const int hp   = by % 6;
    const int n0r  = hp * 128;                 // two heads' weight rows

    const unsigned short* x = (proj == 0) ? xq : (proj == 1) ? xk : xv;
    const unsigned short* W = (proj == 0) ? Wq : (proj == 1) ? Wk : Wv;
    const float* bias       = (proj == 0) ? bq : (proj == 1) ? bk : bv;

    const int w  = tid >> 6;
    const int l  = tid & 63;
    const int c  = l & 15;
    const int g  = l >> 4;
    const int wm = w >> 1;
    const int wn = w & 1;
    const int lr8 = l >> 3;                 // 0..7: row-in-issue
    const int lc8 = (l & 7) ^ lr8;          // pre-swizzled source chunk

    f32x4 acc[4][4] = {};

    for (int kt = 0; kt < EE; kt += 64) {
        __syncthreads();   // prev compute done before overwrite
        #pragma unroll
        for (int i = 0; i < 4; ++i) {       // A: 16 KB = 16 issues, 4/wave
            const int t = w * 4 + i;
            gl16(x + (size_t)(bm + t * 8 + lr8) * EE + kt + lc8 * 8,
                 (unsigned short*)As + t * 512);
        }
        #pragma unroll
        for (int i = 0; i < 4; ++i) {       // B: 16 KB = 16 issues, 4/wave
            const int t = w * 4 + i;
            gl16(W + (size_t)(n0r + t * 8 + lr8) * EE + kt + lc8 * 8,
                 (unsigned short*)Bs + t * 512);
        }
        __syncthreads();   // vmcnt drained by compiler before barrier

        #pragma unroll
        for (int ks = 0; ks < 2; ++ks) {
            short8 bfr[4], afr[4];
            #pragma unroll
            for (int nt = 0; nt < 4; ++nt)
                bfr[nt] = *(const short8*)((const char*)Bs + swz(wn * 64 + nt * 16 + c, ks * 4 + g));
            #pragma unroll
            for (int mt = 0; mt < 4; ++mt)
                afr[mt] = *(const short8*)((const char*)As + swz(wm * 64 + mt * 16 + c, ks * 4 + g));
            #pragma unroll
            for (int mt = 0; mt < 4; ++mt)
                #pragma unroll
                for (int nt = 0; nt < 4; ++nt)
                    acc[mt][nt] = __builtin_amdgcn_mfma_f32_16x16x32_bf16(
                        afr[mt], bfr[nt], acc[mt][nt], 0, 0, 0);
        }
    }
    __syncthreads();   // last tile's frag reads done (needed before V reuses LDS)

    float bb[4];
    #pragma unroll
    for (int nt = 0; nt < 4; ++nt) bb[nt] = bias[n0r + wn * 64 + nt * 16 + c];

    const int bidx  = bm >> 11;
    const int sbase = bm & (SS - 1);
    const int head  = hp * 2 + wn;          // wave's 64 cols = this head

    if (proj < 2) {
        unsigned short* dst = (proj == 0) ? qo : ko;
        // q: fold SCALE * log2(e) so attention uses exp2
        const float fold = (proj == 0) ? 0.18033688f : 1.0f;
        #pragma unroll
        for (int mt = 0; mt < 4; ++mt) {
            f32x4 vr[4];
            #pragma unroll
            for (int nt = 0; nt < 4; ++nt)
                #pragma unroll
                for (int j = 0; j < 4; ++j)
                    vr[nt][j] = acc[mt][nt][j] + bb[nt];
            #pragma unroll
            for (int j = 0; j < 4; ++j) {
                // full-row sum of squares: 4 nt in-lane + 16 lanes (c) shuffle
                float s = vr[0][j]*vr[0][j] + vr[1][j]*vr[1][j]
                        + vr[2][j]*vr[2][j] + vr[3][j]*vr[3][j];
                #pragma unroll
                for (int msk = 1; msk < 16; msk <<= 1) s += __shfl_xor(s, msk);
                const float inv = fold / fmaxf(sqrtf(s), 1e-6f);
                const int rloc = wm * 64 + mt * 16 + g * 4 + j;
                const size_t base =
                    ((size_t)(bidx * HH + head) * SS + sbase + rloc) * DD;
                #pragma unroll
                for (int nt = 0; nt < 4; ++nt)
                    dst[base + nt * 16 + c] = f2bf(vr[nt][j] * inv);
            }
        }
    } else {
        // V: +bias, transpose via SMEM [128 s][128 d], store [bh][d][s]
        #pragma unroll
        for (int mt = 0; mt < 4; ++mt)
            #pragma unroll
            for (int nt = 0; nt < 4; ++nt)
                #pragma unroll
                for (int j = 0; j < 4; ++j) {
                    const int row = wm * 64 + mt * 16 + g * 4 + j;   // s-local
                    const int col = wn * 64 + nt * 16 + c;           // d 0..127
                    SMEM[row * 128 + col] = (short)f2bf(acc[mt][nt][j] + bb[nt]);
                }
        __syncthreads();
        const int d   = tid & 127;            // 0..127 across two heads
        const int sb  = (tid >> 7) * 64;      // 0 or 64
        const int hd  = hp * 2 + (d >> 6);
        const int dd  = d & 63;
        unsigned short* dstp = vo + ((size_t)(bidx * HH + hd) * DD + dd) * SS + sbase + sb;
        #pragma unroll
        for (int grp = 0; grp < 8; ++grp) {
            unsigned int wds[4];
            #pragma unroll
            for (int e = 0; e < 4; ++e) {
                unsigned short u0 = (unsigned short)SMEM[(sb + grp * 8 + 2 * e)     * 128 + d];
                unsigned short u1 = (unsigned short)SMEM[(sb + grp * 8 + 2 * e + 1) * 128 + d];
                wds[e] = (unsigned int)u0 | ((unsigned int)u1 << 16);
            }
            int4 pk = make_int4((int)wds[0], (int)wds[1], (int)wds[2], (int)wds[3]);
            *(int4*)(dstp + grp * 8) = pk;
        }
    }
}

// stage one 64x64 K-tile + 64x64 V-tile into LDS (4 waves: 2 issues each)
static __device__ __forceinline__ void stage_kv4(
    const unsigned short* __restrict__ kbase, const unsigned short* __restrict__ vbase,
    int s0, short* Kbuf, short* Vbuf, int w, int lr8, int lc8)
{
    #pragma unroll
    for (int i = 0; i < 2; ++i) {     // K: 8 issues, 2/wave
        const int t = w * 2 + i;
        gl16(kbase + (size_t)(s0 + t * 8 + lr8) * DD + lc8 * 8,
             (unsigned short*)Kbuf + t * 512);
    }
    #pragma unroll
    for (int i = 0; i < 2; ++i) {     // V: 8 issues, 2/wave
        const int t = w * 2 + i;
        gl16(vbase + (size_t)(t * 8 + lr8) * SS + s0 + lc8 * 8,
             (unsigned short*)Vbuf + t * 512);
    }
}

// ---------------------------------------------------------------------------
// Kernel 2: flash attention, bf16 MFMA, 2-phase dbuf K/V, 4 waves/block.
// (R9 measured form, unchanged.) q,k [bh][s][d]; v transposed [bh][d][s].
// grid (SS/64, B*H), 256 thr; wave owns 16 q-rows.
// q pre-scaled by SCALE*log2e -> P = exp2(sc); no max-tracking (|sc|<=0.19).
// lsum via MFMA with all-ones B (accumulates across tiles in C-regs).
// ---------------------------------------------------------------------------
__global__ __launch_bounds__(256) void attn_mfma_kernel(
    const unsigned short* __restrict__ q, const unsigned short* __restrict__ k,
    const unsigned short* __restrict__ vT, unsigned short* __restrict__ ctx)
{
    __shared__ short Ks[2][64 * 64];     // 16 KB
    __shared__ short Vs[2][64 * 64];     // 16 KB
    __shared__ short Ps[4][16 * 64];     //  8 KB  per-wave [qrow 16][key 64]

    const int tid = threadIdx.x;
    const int bh  = blockIdx.y;
    const int w   = tid >> 6;
    const int l   = tid & 63;
    const int c   = l & 15;
    const int g   = l >> 4;
    const int lr8 = l >> 3;
    const int lc8 = (l & 7) ^ lr8;
    const int qr0 = blockIdx.x * 64 + w * 16;

    const unsigned short* kbase = k  + (size_t)bh * SS * DD;
    const unsigned short* vbase = vT + (size_t)bh * DD * SS;

    // Q A-frags in registers, reused across all KV tiles
    short8 aq[2];
    {
        const unsigned short* qg = q + ((size_t)bh * SS + qr0 + c) * DD;
        aq[0] = *(const short8*)(qg + g * 8);
        aq[1] = *(const short8*)(qg + 32 + g * 8);
    }
    // all-ones bf16 B-frag for row-sum MFMA
    const short one_bf = (short)0x3F80;
    short8 ones = {one_bf, one_bf, one_bf, one_bf, one_bf, one_bf, one_bf, one_bf};

    short* Psw = Ps[w];
    f32x4 o[4] = {};
    f32x4 lacc = {0.f, 0.f, 0.f, 0.f};

    stage_kv4(kbase, vbase, 0, Ks[0], Vs[0], w, lr8, lc8);
    __syncthreads();                         // drain tile-0 loads

    for (int t = 0; t < SS / 64; ++t) {
        const int cur = t & 1;
        if (t + 1 < SS / 64)                 // prefetch next KV tile (async)
            stage_kv4(kbase, vbase, (t + 1) * 64, Ks[cur ^ 1], Vs[cur ^ 1], w, lr8, lc8);

        // QK^T: rows=q (g*4+j), cols=key (c)
        f32x4 sc[4] = {};
        #pragma unroll
        for (int ks = 0; ks < 2; ++ks)
            #pragma unroll
            for (int nt = 0; nt < 4; ++nt) {
                short8 kf = *(const short8*)((const char*)Ks[cur] + swz(nt * 16 + c, ks * 4 + g));
                sc[nt] = __builtin_amdgcn_mfma_f32_16x16x32_bf16(aq[ks], kf, sc[nt], 0, 0, 0);
            }

        // P = exp2(sc) (log2e folded into q), -> bf16 -> per-wave LDS
        #pragma unroll
        for (int nt = 0; nt < 4; ++nt)
            #pragma unroll
            for (int j = 0; j < 4; ++j) {
                const float p = __builtin_exp2f(sc[nt][j]);
                const int row = g * 4 + j;
                const int ch  = (nt * 2 + (c >> 3)) ^ (row & 7);
                Psw[row * 64 + (ch << 3) + (c & 7)] = (short)f2bf(p);
            }

        // PV + denominator (lacc += P . ones)
        #pragma unroll
        for (int ks = 0; ks < 2; ++ks) {
            short8 pa = *(const short8*)((const char*)Psw + swz(c, ks * 4 + g));
            lacc = __builtin_amdgcn_mfma_f32_16x16x32_bf16(pa, ones, lacc, 0, 0, 0);
            #pragma unroll
            for (int dt = 0; dt < 4; ++dt) {
                short8 vf = *(const short8*)((const char*)Vs[cur] + swz(dt * 16 + c, ks * 4 + g));
                o[dt] = __builtin_amdgcn_mfma_f32_16x16x32_bf16(pa, vf, o[dt], 0, 0, 0);
            }
        }
        __syncthreads();   // one barrier/tile: drains prefetch AFTER compute
    }

    // epilogue: divide by denom (lacc cols all equal), store ctx bf16 [b][s][e]
    const int bidx = bh / HH, h = bh % HH;
    #pragma unroll
    for (int j = 0; j < 4; ++j) {
        const float inv = 1.0f / lacc[j];
        const int sg = qr0 + g * 4 + j;
        unsigned short* op = ctx + ((size_t)bidx * SS + sg) * EE + h * DD + c;
        #pragma unroll
        for (int dt = 0; dt < 4; ++dt)
            op[dt * 16] = f2bf(o[dt][j] * inv);
    }
}

// ---------------------------------------------------------------------------
// Kernel 3: output projection, MFMA, single-buffered (R5/R9 measured form).
// out = ctx(bf16) @ Wo.T + bo (fp32 out). grid (MM/128, EE/64).
// ---------------------------------------------------------------------------
__global__ __launch_bounds__(256) void out_mfma_kernel(
    const unsigned short* __restrict__ A, const unsigned short* __restrict__ W,
    const float* __restrict__ bias, float* __restrict__ out)
{
    __shared__ short As[128 * 64];
    __shared__ short Bs[64 * 64];

    const int tid = threadIdx.x;
    const int bm  = blockIdx.x * 128;
    const int n0  = blockIdx.y * 64;

    const int w  = tid >> 6;
    const int l  = tid & 63;
    const int c  = l & 15;
    const int g  = l >> 4;
    const int wm = w >> 1;
    const int wn = w & 1;
    const int lr8 = l >> 3;
    const int lc8 = (l & 7) ^ lr8;

    f32x4 acc[4][2] = {};

    for (int kt = 0; kt < EE; kt += 64) {
        __syncthreads();
        #pragma unroll
        for (int i = 0; i < 4; ++i) {
            const int t = w * 4 + i;
            gl16(A + (size_t)(bm + t * 8 + lr8) * EE + kt + lc8 * 8,
                 (unsigned short*)As + t * 512);
        }
        #pragma unroll
        for (int i = 0; i < 2; ++i) {
            const int t = w * 2 + i;
            gl16(W + (size_t)(n0 + t * 8 + lr8) * EE + kt + lc8 * 8,
                 (unsigned short*)Bs + t * 512);
        }
        __syncthreads();

        #pragma unroll
        for (int ks = 0; ks < 2; ++ks) {
            short8 bfr[2], afr[4];
            #pragma unroll
            for (int nt = 0; nt < 2; ++nt)
                bfr[nt] = *(const short8*)((const char*)Bs + swz(wn * 32 + nt * 16 + c, ks * 4 + g));
            #pragma unroll
            for (int mt = 0; mt < 4; ++mt)
                afr[mt] = *(const short8*)((const char*)As + swz(wm * 64 + mt * 16 + c, ks * 4 + g));
            #pragma unroll
            for (int mt = 0; mt < 4; ++mt)
                #pragma unroll
                for (int nt = 0; nt < 2; ++nt)
                    acc[mt][nt] = __builtin_amdgcn_mfma_f32_16x16x32_bf16(
                        afr[mt], bfr[nt], acc[mt][nt], 0, 0, 0);
        }
    }

    float bb[2];
    #pragma unroll
    for (int nt = 0; nt < 2; ++nt) bb[nt] = bias[n0 + wn * 32 + nt * 16 + c];

    #pragma unroll
    for (int mt = 0; mt < 4; ++mt)
        #pragma unroll
        for (int j = 0; j < 4; ++j) {
            const int row = bm + wm * 64 + mt * 16 + g * 4 + j;
            float* op = out + (size_t)row * EE + n0 + wn * 32 + c;
            #pragma unroll
            for (int nt = 0; nt < 2; ++nt)
                op[nt * 16] = acc[mt][nt][j] + bb[nt];
        }
}

// ---------------------------------------------------------------------------
extern "C" void kernel_launch(void* const* d_in, const int* in_sizes, int n_in,
                              void* d_out, int out_size, void* d_ws, size_t ws_size,
                              hipStream_t stream)
{
    const float* query = (const float*)d_in[0];
    const float* key   = (const float*)d_in[1];
    const float* value = (const float*)d_in[2];
    const float* Wq = (const float*)d_in[3];
    const float* bq = (const float*)d_in[4];
    const float* Wk = (const float*)d_in[5];
    const float* bk = (const float*)d_in[6];
    const float* Wv = (const float*)d_in[7];
    const float* bv = (const float*)d_in[8];
    const float* Wo = (const float*)d_in[9];
    const float* bo = (const float*)d_in[10];
    float* out = (float*)d_out;

    // ws: xqc/xkc/xvc (bf16 inputs), q/k/vT (bf16 heads), W's bf16.
    // ctx aliases xqc (qkv consumed it before attn writes; stream-ordered).
    unsigned short* xqc  = (unsigned short*)d_ws;
    unsigned short* xkc  = xqc  + NT;
    unsigned short* xvc  = xkc  + NT;
    unsigned short* qws  = xvc  + NT;
    unsigned short* kws  = qws  + NT;
    unsigned short* vtws = kws  + NT;
    unsigned short* wqc  = vtws + NT;
    unsigned short* wkc  = wqc  + NW;
    unsigned short* wvc  = wkc  + NW;
    unsigned short* woc  = wvc  + NW;
    unsigned short* ctx  = xqc;          // alias

    const int cvt_blocks = (3 * (NT / 4) + 4 * (NW / 4)) / 256;   // 11520
    cvt_all_kernel<<<dim3(cvt_blocks), 256, 0, stream>>>(
        query, key, value, Wq, Wk, Wv, Wo,
        xqc, xkc, xvc, wqc, wkc, wvc, woc);
    qkv_mfma_kernel<<<dim3(MM / 128, 18), 256, 0, stream>>>(
        xqc, xkc, xvc, wqc, bq, wkc, bk, wvc, bv, qws, kws, vtws);
    attn_mfma_kernel<<<dim3(SS / 64, BB * HH), 256, 0, stream>>>(
        qws, kws, vtws, ctx);
    out_mfma_kernel<<<dim3(MM / 128, EE / 64), 256, 0, stream>>>(
        ctx, woc, bo, out);
}

// Round 11
// 199.844 us; speedup vs baseline: 1.0539x; 1.0539x over previous
//
#include <hip/hip_runtime.h>
#include <hip/hip_bf16.h>

#define EE 768
#define HH 12
#define DD 64
#define BB 2
#define SS 2048
#define MM (BB*SS)          // 4096
#define NT (MM*EE)          // 3,145,728 elements (also B*H*S*D)
#define NW (EE*EE)          // 589,824

typedef short short8 __attribute__((ext_vector_type(8)));   // 8 bf16 = 4 VGPR (MFMA A/B frag)
typedef float f32x4 __attribute__((ext_vector_type(4)));    // MFMA C/D frag

static __device__ __forceinline__ unsigned short f2bf(float f) {
    unsigned int u = __float_as_uint(f);
    u += 0x7fffu + ((u >> 16) & 1u);      // round-to-nearest-even
    return (unsigned short)(u >> 16);
}

// v_cvt_pk_bf16_f32: packs 2 f32 -> 2 bf16 in one u32 (lo -> bits[15:0]).
// No builtin on gfx950 (m240) -> inline asm, HK/T12 recipe.
static __device__ __forceinline__ unsigned int cvtpk_bf16(float lo, float hi) {
    unsigned int r;
    asm("v_cvt_pk_bf16_f32 %0, %1, %2" : "=v"(r) : "v"(lo), "v"(hi));
    return r;
}

// async 16B global->LDS. LDS dest = wave-uniform base + lane*16 (HW rule).
static __device__ __forceinline__ void gl16(const void* g, void* l) {
    __builtin_amdgcn_global_load_lds(
        (const __attribute__((address_space(1))) unsigned int*)g,
        (__attribute__((address_space(3))) unsigned int*)l, 16, 0, 0);
}

// Swizzled byte offset in a [R][64] bf16 LDS tile (128B rows, 8x16B chunks).
// Staging pre-swizzles the per-lane GLOBAL source chunk ((l&7)^(l>>3)) so the
// linear gl16 dest holds swizzled content; reads via swz() are conflict-free
// (rule #21: both-sides-or-neither).
static __device__ __forceinline__ int swz(int row, int chunk) {
    return row * 128 + ((chunk ^ (row & 7)) << 4);
}

// ---------------------------------------------------------------------------
// fp32 -> bf16 pre-convert, all 7 tensors in one launch (memory-bound).
// ---------------------------------------------------------------------------
__global__ __launch_bounds__(256) void cvt_all_kernel(
    const float* __restrict__ xq, const float* __restrict__ xk, const float* __restrict__ xv,
    const float* __restrict__ wq, const float* __restrict__ wk,
    const float* __restrict__ wv, const float* __restrict__ wo,
    unsigned short* __restrict__ oq, unsigned short* __restrict__ ok, unsigned short* __restrict__ ov,
    unsigned short* __restrict__ owq, unsigned short* __restrict__ owk,
    unsigned short* __restrict__ owv, unsigned short* __restrict__ owo)
{
    const int XQ = NT / 4;   // quads per x tensor
    const int WQ = NW / 4;   // quads per W tensor
    const int idx = blockIdx.x * 256 + threadIdx.x;
    const float* s;
    unsigned short* d;
    int off;
    if (idx < 3 * XQ) {
        const int r = idx / XQ;
        off = idx - r * XQ;
        s = (r == 0) ? xq : (r == 1) ? xk : xv;
        d = (r == 0) ? oq : (r == 1) ? ok : ov;
    } else {
        const int j = idx - 3 * XQ;
        const int r = j / WQ;
        off = j - r * WQ;
        s = (r == 0) ? wq : (r == 1) ? wk : (r == 2) ? wv : wo;
        d = (r == 0) ? owq : (r == 1) ? owk : (r == 2) ? owv : owo;
    }
    float4 f = ((const float4*)s)[off];
    ushort4 u;
    u.x = f2bf(f.x); u.y = f2bf(f.y); u.z = f2bf(f.z); u.w = f2bf(f.w);
    ((ushort4*)d)[off] = u;
}

// ---------------------------------------------------------------------------
// Kernel 1: QKV projection, MFMA, single-buffered gl16 staging (R9 measured
// form: BN=64, 1152 blocks = 4.5/CU; BN=128 regressed -8us, R10).
// grid (MM/128, 36): by 0-11 q(head), 12-23 k, 24-35 v.
// BM=128 BN=64 BK=64, 256 thr = 4 waves (2Mx2N), per-wave 64x32.
// Epilogue: +bias; q/k l2-norm over head; q additionally folds SCALE*log2e so
// attention can use exp2 directly. v -> transposed bf16 [bh][d][s] via LDS.
// ---------------------------------------------------------------------------
__global__ __launch_bounds__(256) void qkv_mfma_kernel(
    const unsigned short* __restrict__ xq, const unsigned short* __restrict__ xk,
    const unsigned short* __restrict__ xv,
    const unsigned short* __restrict__ Wq, const float* __restrict__ bq,
    const unsigned short* __restrict__ Wk, const float* __restrict__ bk,
    const unsigned short* __restrict__ Wv, const float* __restrict__ bv,
    unsigned short* __restrict__ qo, unsigned short* __restrict__ ko,
    unsigned short* __restrict__ vo)
{
    __shared__ short As[128 * 64];   // 16 KB
    __shared__ short Bs[64 * 64];    //  8 KB
    __shared__ float ssq[2][128];    //  1 KB

    const int tid = threadIdx.x;
    const int bm  = blockIdx.x * 128;
    const int by  = blockIdx.y;
    const int proj = by / 12;
    const int h    = by % 12;
    const int n0r  = h * 64;

    const unsigned short* x = (proj == 0) ? xq : (proj == 1) ? xk : xv;
    const unsigned short* W = (proj == 0) ? Wq : (proj == 1) ? Wk : Wv;
    const float* bias       = (proj == 0) ? bq : (proj == 1) ? bk : bv;

    const int w  = tid >> 6;
    const int l  = tid & 63;
    const int c  = l & 15;
    const int g  = l >> 4;
    const int wm = w >> 1;
    const int wn = w & 1;
    const int lr8 = l >> 3;                 // 0..7: row-in-issue
    const int lc8 = (l & 7) ^ lr8;          // pre-swizzled source chunk

    f32x4 acc[4][2] = {};

    for (int kt = 0; kt < EE; kt += 64) {
        __syncthreads();   // prev compute done before overwrite
        #pragma unroll
        for (int i = 0; i < 4; ++i) {       // A: 16 issues, 4/wave
            const int t = w * 4 + i;
            gl16(x + (size_t)(bm + t * 8 + lr8) * EE + kt + lc8 * 8,
                 (unsigned short*)As + t * 512);
        }
        #pragma unroll
        for (int i = 0; i < 2; ++i) {       // B: 8 issues, 2/wave
            const int t = w * 2 + i;
            gl16(W + (size_t)(n0r + t * 8 + lr8) * EE + kt + lc8 * 8,
                 (unsigned short*)Bs + t * 512);
        }
        __syncthreads();   // vmcnt drained by compiler before barrier

        #pragma unroll
        for (int ks = 0; ks < 2; ++ks) {
            short8 bfr[2], afr[4];
            #pragma unroll
            for (int nt = 0; nt < 2; ++nt)
                bfr[nt] = *(const short8*)((const char*)Bs + swz(wn * 32 + nt * 16 + c, ks * 4 + g));
            #pragma unroll
            for (int mt = 0; mt < 4; ++mt)
                afr[mt] = *(const short8*)((const char*)As + swz(wm * 64 + mt * 16 + c, ks * 4 + g));
            #pragma unroll
            for (int mt = 0; mt < 4; ++mt)
                #pragma unroll
                for (int nt = 0; nt < 2; ++nt)
                    acc[mt][nt] = __builtin_amdgcn_mfma_f32_16x16x32_bf16(
                        afr[mt], bfr[nt], acc[mt][nt], 0, 0, 0);
        }
    }
    __syncthreads();

    float bb[2];
    #pragma unroll
    for (int nt = 0; nt < 2; ++nt) bb[nt] = bias[n0r + wn * 32 + nt * 16 + c];

    const int bidx  = bm >> 11;
    const int sbase = bm & (SS - 1);

    if (proj < 2) {
        f32x4 vr[4][2];
        f32x4 ssp[4];
        #pragma unroll
        for (int mt = 0; mt < 4; ++mt) {
            #pragma unroll
            for (int nt = 0; nt < 2; ++nt)
                #pragma unroll
                for (int j = 0; j < 4; ++j)
                    vr[mt][nt][j] = acc[mt][nt][j] + bb[nt];
            #pragma unroll
            for (int j = 0; j < 4; ++j)
                ssp[mt][j] = vr[mt][0][j]*vr[mt][0][j] + vr[mt][1][j]*vr[mt][1][j];
            #pragma unroll
            for (int j = 0; j < 4; ++j) {
                float s = ssp[mt][j];
                #pragma unroll
                for (int msk = 1; msk < 16; msk <<= 1) s += __shfl_xor(s, msk);
                ssp[mt][j] = s;
            }
        }
        if (c == 0) {
            #pragma unroll
            for (int mt = 0; mt < 4; ++mt)
                #pragma unroll
                for (int j = 0; j < 4; ++j)
                    ssq[wn][wm * 64 + mt * 16 + g * 4 + j] = ssp[mt][j];
        }
        __syncthreads();
        unsigned short* dst = (proj == 0) ? qo : ko;
        // q: fold SCALE * log2(e) so attention uses exp2 (saves a mul per elem)
        const float fold = (proj == 0) ? 0.18033688f : 1.0f;
        #pragma unroll
        for (int mt = 0; mt < 4; ++mt) {
            #pragma unroll
            for (int j = 0; j < 4; ++j) {
                const int rloc = wm * 64 + mt * 16 + g * 4 + j;
                const float ss = ssq[0][rloc] + ssq[1][rloc];
                const float inv = fold / fmaxf(sqrtf(ss), 1e-6f);
                const size_t base =
                    ((size_t)(bidx * HH + h) * SS + sbase + rloc) * DD;
                #pragma unroll
                for (int nt = 0; nt < 2; ++nt)
                    dst[base + wn * 32 + nt * 16 + c] = f2bf(vr[mt][nt][j] * inv);
            }
        }
    } else {
        // V: +bias, transpose via LDS (reuse As as [128 s][64 d]), store [bh][d][s]
        #pragma unroll
        for (int mt = 0; mt < 4; ++mt)
            #pragma unroll
            for (int nt = 0; nt < 2; ++nt)
                #pragma unroll
                for (int j = 0; j < 4; ++j) {
                    const int row = wm * 64 + mt * 16 + g * 4 + j;
                    const int col = wn * 32 + nt * 16 + c;
                    As[row * 64 + col] = (short)f2bf(acc[mt][nt][j] + bb[nt]);
                }
        __syncthreads();
        const int d  = tid & 63;
        const int sb = (tid >> 6) * 32;
        unsigned short* dstp = vo + ((size_t)(bidx * HH + h) * DD + d) * SS + sbase + sb;
        #pragma unroll
        for (int grp = 0; grp < 4; ++grp) {
            unsigned int wds[4];
            #pragma unroll
            for (int e = 0; e < 4; ++e) {
                unsigned short u0 = (unsigned short)As[(sb + grp * 8 + 2 * e)     * 64 + d];
                unsigned short u1 = (unsigned short)As[(sb + grp * 8 + 2 * e + 1) * 64 + d];
                wds[e] = (unsigned int)u0 | ((unsigned int)u1 << 16);
            }
            int4 pk = make_int4((int)wds[0], (int)wds[1], (int)wds[2], (int)wds[3]);
            *(int4*)(dstp + grp * 8) = pk;
        }
    }
}

// stage one 64x64 K-tile + 64x64 V-tile into LDS (4 waves: 2 issues each)
static __device__ __forceinline__ void stage_kv4(
    const unsigned short* __restrict__ kbase, const unsigned short* __restrict__ vbase,
    int s0, short* Kbuf, short* Vbuf, int w, int lr8, int lc8)
{
    #pragma unroll
    for (int i = 0; i < 2; ++i) {     // K: 8 issues, 2/wave
        const int t = w * 2 + i;
        gl16(kbase + (size_t)(s0 + t * 8 + lr8) * DD + lc8 * 8,
             (unsigned short*)Kbuf + t * 512);
    }
    #pragma unroll
    for (int i = 0; i < 2; ++i) {     // V: 8 issues, 2/wave
        const int t = w * 2 + i;
        gl16(vbase + (size_t)(t * 8 + lr8) * SS + s0 + lc8 * 8,
             (unsigned short*)Vbuf + t * 512);
    }
}

// ---------------------------------------------------------------------------
// Kernel 2: flash attention, bf16 MFMA, 2-phase dbuf K/V, 4 waves/block.
// SWAPPED QK^T (T12): sc[nt] = mfma(K-frag, Q-frag) -> lane (c,g) holds
// S[q=c][key=nt*16+g*4+j]: a contiguous 4-key run in P-row c. P-store becomes
// 8 cvt_pk + 4 ds_write_b64 (was 16 f2bf + 16 scattered b16 writes).
// PV reads / lacc-ones / epilogue identical to R9 measured form.
// q pre-scaled by SCALE*log2e -> P = exp2(sc); no max-tracking (|sc|<=0.19).
// ---------------------------------------------------------------------------
__global__ __launch_bounds__(256) void attn_mfma_kernel(
    const unsigned short* __restrict__ q, const unsigned short* __restrict__ k,
    const unsigned short* __restrict__ vT, unsigned short* __restrict__ ctx)
{
    __shared__ short Ks[2][64 * 64];     // 16 KB
    __shared__ short Vs[2][64 * 64];     // 16 KB
    __shared__ short Ps[4][16 * 64];     //  8 KB  per-wave [qrow 16][key 64]

    const int tid = threadIdx.x;
    const int bh  = blockIdx.y;
    const int w   = tid >> 6;
    const int l   = tid & 63;
    const int c   = l & 15;
    const int g   = l >> 4;
    const int lr8 = l >> 3;
    const int lc8 = (l & 7) ^ lr8;
    const int qr0 = blockIdx.x * 64 + w * 16;

    const unsigned short* kbase = k  + (size_t)bh * SS * DD;
    const unsigned short* vbase = vT + (size_t)bh * DD * SS;

    // Q frags in registers, reused across all KV tiles (B-operand now)
    short8 aq[2];
    {
        const unsigned short* qg = q + ((size_t)bh * SS + qr0 + c) * DD;
        aq[0] = *(const short8*)(qg + g * 8);
        aq[1] = *(const short8*)(qg + 32 + g * 8);
    }
    // all-ones bf16 B-frag for row-sum MFMA
    const short one_bf = (short)0x3F80;
    short8 ones = {one_bf, one_bf, one_bf, one_bf, one_bf, one_bf, one_bf, one_bf};

    short* Psw = Ps[w];
    f32x4 o[4] = {};
    f32x4 lacc = {0.f, 0.f, 0.f, 0.f};

    // P-store address: row c, keys nt*16+4g..+3 -> chunk 2nt+(g>>1) (xor c&7),
    // 8B half (g&1). One b64 per nt. <=2-way banks (free, m136).
    const int pbase = c * 128 + (g & 1) * 8;
    const int pxor  = (c & 7) << 4;

    stage_kv4(kbase, vbase, 0, Ks[0], Vs[0], w, lr8, lc8);
    __syncthreads();                         // drain tile-0 loads

    for (int t = 0; t < SS / 64; ++t) {
        const int cur = t & 1;
        if (t + 1 < SS / 64)                 // prefetch next KV tile (async)
            stage_kv4(kbase, vbase, (t + 1) * 64, Ks[cur ^ 1], Vs[cur ^ 1], w, lr8, lc8);

        // QK^T, swapped operands: A=K-frag (i=key), B=Q-frag (j=q-row)
        f32x4 sc[4] = {};
        #pragma unroll
        for (int ks = 0; ks < 2; ++ks)
            #pragma unroll
            for (int nt = 0; nt < 4; ++nt) {
                short8 kf = *(const short8*)((const char*)Ks[cur] + swz(nt * 16 + c, ks * 4 + g));
                sc[nt] = __builtin_amdgcn_mfma_f32_16x16x32_bf16(kf, aq[ks], sc[nt], 0, 0, 0);
            }

        // P = exp2(sc); lane (c,g) owns keys {nt*16+g*4+j} of P-row c:
        // pack 4 -> one ds_write_b64 per nt.
        #pragma unroll
        for (int nt = 0; nt < 4; ++nt) {
            uint2 pk;
            pk.x = cvtpk_bf16(__builtin_exp2f(sc[nt][0]), __builtin_exp2f(sc[nt][1]));
            pk.y = cvtpk_bf16(__builtin_exp2f(sc[nt][2]), __builtin_exp2f(sc[nt][3]));
            const int ch = (2 * nt + (g >> 1)) << 4;
            *(uint2*)((char*)Psw + pbase + (ch ^ pxor)) = pk;
        }

        // PV + denominator (lacc += P . ones)
        #pragma unroll
        for (int ks = 0; ks < 2; ++ks) {
            short8 pa = *(const short8*)((const char*)Psw + swz(c, ks * 4 + g));
            lacc = __builtin_amdgcn_mfma_f32_16x16x32_bf16(pa, ones, lacc, 0, 0, 0);
            #pragma unroll
            for (int dt = 0; dt < 4; ++dt) {
                short8 vf = *(const short8*)((const char*)Vs[cur] + swz(dt * 16 + c, ks * 4 + g));
                o[dt] = __builtin_amdgcn_mfma_f32_16x16x32_bf16(pa, vf, o[dt], 0, 0, 0);
            }
        }
        __syncthreads();   // one barrier/tile: drains prefetch AFTER compute
    }

    // epilogue: divide by denom (lacc cols all equal), store ctx bf16 [b][s][e]
    const int bidx = bh / HH, h = bh % HH;
    #pragma unroll
    for (int j = 0; j < 4; ++j) {
        const float inv = 1.0f / lacc[j];
        const int sg = qr0 + g * 4 + j;
        unsigned short* op = ctx + ((size_t)bidx * SS + sg) * EE + h * DD + c;
        #pragma unroll
        for (int dt = 0; dt < 4; ++dt)
            op[dt * 16] = f2bf(o[dt][j] * inv);
    }
}

// ---------------------------------------------------------------------------
// Kernel 3: output projection, MFMA, single-buffered (R5/R9 measured form).
// out = ctx(bf16) @ Wo.T + bo (fp32 out). grid (MM/128, EE/64).
// ---------------------------------------------------------------------------
__global__ __launch_bounds__(256) void out_mfma_kernel(
    const unsigned short* __restrict__ A, const unsigned short* __restrict__ W,
    const float* __restrict__ bias, float* __restrict__ out)
{
    __shared__ short As[128 * 64];
    __shared__ short Bs[64 * 64];

    const int tid = threadIdx.x;
    const int bm  = blockIdx.x * 128;
    const int n0  = blockIdx.y * 64;

    const int w  = tid >> 6;
    const int l  = tid & 63;
    const int c  = l & 15;
    const int g  = l >> 4;
    const int wm = w >> 1;
    const int wn = w & 1;
    const int lr8 = l >> 3;
    const int lc8 = (l & 7) ^ lr8;

    f32x4 acc[4][2] = {};

    for (int kt = 0; kt < EE; kt += 64) {
        __syncthreads();
        #pragma unroll
        for (int i = 0; i < 4; ++i) {
            const int t = w * 4 + i;
            gl16(A + (size_t)(bm + t * 8 + lr8) * EE + kt + lc8 * 8,
                 (unsigned short*)As + t * 512);
        }
        #pragma unroll
        for (int i = 0; i < 2; ++i) {
            const int t = w * 2 + i;
            gl16(W + (size_t)(n0 + t * 8 + lr8) * EE + kt + lc8 * 8,
                 (unsigned short*)Bs + t * 512);
        }
        __syncthreads();

        #pragma unroll
        for (int ks = 0; ks < 2; ++ks) {
            short8 bfr[2], afr[4];
            #pragma unroll
            for (int nt = 0; nt < 2; ++nt)
                bfr[nt] = *(const short8*)((const char*)Bs + swz(wn * 32 + nt * 16 + c, ks * 4 + g));
            #pragma unroll
            for (int mt = 0; mt < 4; ++mt)
                afr[mt] = *(const short8*)((const char*)As + swz(wm * 64 + mt * 16 + c, ks * 4 + g));
            #pragma unroll
            for (int mt = 0; mt < 4; ++mt)
                #pragma unroll
                for (int nt = 0; nt < 2; ++nt)
                    acc[mt][nt] = __builtin_amdgcn_mfma_f32_16x16x32_bf16(
                        afr[mt], bfr[nt], acc[mt][nt], 0, 0, 0);
        }
    }

    float bb[2];
    #pragma unroll
    for (int nt = 0; nt < 2; ++nt) bb[nt] = bias[n0 + wn * 32 + nt * 16 + c];

    #pragma unroll
    for (int mt = 0; mt < 4; ++mt)
        #pragma unroll
        for (int j = 0; j < 4; ++j) {
            const int row = bm + wm * 64 + mt * 16 + g * 4 + j;
            float* op = out + (size_t)row * EE + n0 + wn * 32 + c;
            #pragma unroll
            for (int nt = 0; nt < 2; ++nt)
                op[nt * 16] = acc[mt][nt][j] + bb[nt];
        }
}

// ---------------------------------------------------------------------------
extern "C" void kernel_launch(void* const* d_in, const int* in_sizes, int n_in,
                              void* d_out, int out_size, void* d_ws, size_t ws_size,
                              hipStream_t stream)
{
    const float* query = (const float*)d_in[0];
    const float* key   = (const float*)d_in[1];
    const float* value = (const float*)d_in[2];
    const float* Wq = (const float*)d_in[3];
    const float* bq = (const float*)d_in[4];
    const float* Wk = (const float*)d_in[5];
    const float* bk = (const float*)d_in[6];
    const float* Wv = (const float*)d_in[7];
    const float* bv = (const float*)d_in[8];
    const float* Wo = (const float*)d_in[9];
    const float* bo = (const float*)d_in[10];
    float* out = (float*)d_out;

    // ws: xqc/xkc/xvc (bf16 inputs), q/k/vT (bf16 heads), W's bf16.
    // ctx aliases xqc (qkv consumed it before attn writes; stream-ordered).
    unsigned short* xqc  = (unsigned short*)d_ws;
    unsigned short* xkc  = xqc  + NT;
    unsigned short* xvc  = xkc  + NT;
    unsigned short* qws  = xvc  + NT;
    unsigned short* kws  = qws  + NT;
    unsigned short* vtws = kws  + NT;
    unsigned short* wqc  = vtws + NT;
    unsigned short* wkc  = wqc  + NW;
    unsigned short* wvc  = wkc  + NW;
    unsigned short* woc  = wvc  + NW;
    unsigned short* ctx  = xqc;          // alias

    const int cvt_blocks = (3 * (NT / 4) + 4 * (NW / 4)) / 256;   // 11520
    cvt_all_kernel<<<dim3(cvt_blocks), 256, 0, stream>>>(
        query, key, value, Wq, Wk, Wv, Wo,
        xqc, xkc, xvc, wqc, wkc, wvc, woc);
    qkv_mfma_kernel<<<dim3(MM / 128, 36), 256, 0, stream>>>(
        xqc, xkc, xvc, wqc, bq, wkc, bk, wvc, bv, qws, kws, vtws);
    attn_mfma_kernel<<<dim3(SS / 64, BB * HH), 256, 0, stream>>>(
        qws, kws, vtws, ctx);
    out_mfma_kernel<<<dim3(MM / 128, EE / 64), 256, 0, stream>>>(
        ctx, woc, bo, out);
}